// Round 2
// baseline (806.488 us; speedup 1.0000x reference)
//
#include <hip/hip_runtime.h>
#include <math.h>

#define LEAK 0.01f

// ---------------------------------------------------------------------------
// Geometry:
//   high_level: [4,256,128,128]  low_level: [4,64,256,256]  emb: [4,256,256,256]
//   H = W = 256, 65536 px/image, 262144 px total
//
// ws layout (float indices):
//   cat  : [4][4 groups][65536][16]  at 0        (16,777,216 floats) group-chunked NHWC16
//   pre  : [262144][16]  at 16777216             ( 4,194,304 floats) NHWC16
//   wbuf at 20971520:
//     rwt  [128][64]  +0      (8192)  rwt[c][o] = reduce_w[o*128+c]
//     c1t  [64][16]   +8192   (1024)
//     ect  [256][16]  +9216   (4096)
//     w2t  [9][16][36]+13312  (5184)  w2t[k][i][o] = conv2_w[o][i][ky][kx]
//     owt  [64][32]   +18496  (2048)  BN-folded: out_w[o][c]*gamma[o]*rsqrt(var+eps)
//     obias[32]       +20544         BN-folded bias
// ---------------------------------------------------------------------------
#define WS_PRE_OFF 16777216
#define WS_W_OFF   20971520

__global__ __launch_bounds__(256) void k0_transpose(
    const float* __restrict__ reduce_w, const float* __restrict__ conv1_w,
    const float* __restrict__ embconv_w, const float* __restrict__ conv2_w,
    const float* __restrict__ out_w, const float* __restrict__ out_b,
    const float* __restrict__ bn_gamma, const float* __restrict__ bn_beta,
    const float* __restrict__ bn_mean, const float* __restrict__ bn_var,
    float* __restrict__ wbuf) {
  int idx = blockIdx.x * 256 + threadIdx.x;
  if (idx < 8192) {
    int c = idx >> 6, o = idx & 63;
    wbuf[idx] = reduce_w[o * 128 + c];
  } else if (idx < 9216) {
    int i2 = idx - 8192; int c = i2 >> 4, j = i2 & 15;
    wbuf[idx] = conv1_w[j * 64 + c];
  } else if (idx < 13312) {
    int i2 = idx - 9216; int c = i2 >> 4, j = i2 & 15;
    wbuf[idx] = embconv_w[j * 256 + c];
  } else if (idx < 18496) {
    int i2 = idx - 13312;
    int o = i2 % 36; int r = i2 / 36; int i = r & 15; int kk = r >> 4;
    wbuf[idx] = conv2_w[(o * 16 + i) * 9 + kk];
  } else if (idx < 20544) {
    int i2 = idx - 18496; int c = i2 >> 5, o = i2 & 31;
    float sc = bn_gamma[o] * rsqrtf(bn_var[o] + 1e-5f);
    wbuf[idx] = out_w[o * 64 + c] * sc;
  } else if (idx < 20576) {
    int o = idx - 20544;
    float sc = bn_gamma[o] * rsqrtf(bn_var[o] + 1e-5f);
    wbuf[idx] = (out_b[o] - bn_mean[o]) * sc + bn_beta[o];
  }
}

// ---------------------------------------------------------------------------
// KA: fused pixel_shuffle + concat + reduce(128->64) + conv1(64->16)
//     + embconv(256->16) + leaky  ->  cat (grouped NHWC16), pre (NHWC16)
// ---------------------------------------------------------------------------
__global__ __launch_bounds__(256) void ka_fused(
    const float* __restrict__ high, const float* __restrict__ low,
    const float* __restrict__ emb,
    const float* __restrict__ reduce_b, const float* __restrict__ conv1_b,
    const float* __restrict__ embconv_b,
    const float* __restrict__ wbuf,
    float* __restrict__ cat_out, float* __restrict__ pre_out) {
  const float* rwt = wbuf;              // [128][64]
  const float* c1t = wbuf + 8192;       // [64][16]
  const float* ect = wbuf + 9216;       // [256][16]

  int pix = blockIdx.x * 256 + threadIdx.x;
  int b   = pix >> 16;
  int rem = pix & 65535;
  int y   = rem >> 8, x = rem & 255;

  float acc[64];
#pragma unroll
  for (int o = 0; o < 64; ++o) acc[o] = reduce_b[o];

  // ---- reduce: pixel_shuffle(high) channels 0..63 ----
  int lane_off = ((x & 1) << 14) + (x >> 1);                       // plane 128*128
  int hb = (b * 256 + ((y & 1) << 1)) * 16384 + ((y >> 1) << 7);   // + c*65536
#pragma unroll 8
  for (int c = 0; c < 64; ++c) {
    float xv = high[hb + c * 65536 + lane_off];
    const float* wr = rwt + c * 64;
#pragma unroll
    for (int o4 = 0; o4 < 16; ++o4) {
      float4 w = *(const float4*)(wr + o4 * 4);
      acc[o4 * 4 + 0] = fmaf(w.x, xv, acc[o4 * 4 + 0]);
      acc[o4 * 4 + 1] = fmaf(w.y, xv, acc[o4 * 4 + 1]);
      acc[o4 * 4 + 2] = fmaf(w.z, xv, acc[o4 * 4 + 2]);
      acc[o4 * 4 + 3] = fmaf(w.w, xv, acc[o4 * 4 + 3]);
    }
  }
  // ---- reduce: low channels 64..127 ----
  int lb = b * 64 * 65536 + rem;
#pragma unroll 8
  for (int c = 0; c < 64; ++c) {
    float xv = low[lb + c * 65536];
    const float* wr = rwt + (64 + c) * 64;
#pragma unroll
    for (int o4 = 0; o4 < 16; ++o4) {
      float4 w = *(const float4*)(wr + o4 * 4);
      acc[o4 * 4 + 0] = fmaf(w.x, xv, acc[o4 * 4 + 0]);
      acc[o4 * 4 + 1] = fmaf(w.y, xv, acc[o4 * 4 + 1]);
      acc[o4 * 4 + 2] = fmaf(w.z, xv, acc[o4 * 4 + 2]);
      acc[o4 * 4 + 3] = fmaf(w.w, xv, acc[o4 * 4 + 3]);
    }
  }

  // ---- store cat (group-chunked NHWC16) ----
#pragma unroll
  for (int g = 0; g < 4; ++g) {
    float* cp = cat_out + (((size_t)(b * 4 + g) << 16) + rem) * 16;
#pragma unroll
    for (int o4 = 0; o4 < 4; ++o4) {
      float4 v;
      v.x = acc[g * 16 + o4 * 4 + 0]; v.y = acc[g * 16 + o4 * 4 + 1];
      v.z = acc[g * 16 + o4 * 4 + 2]; v.w = acc[g * 16 + o4 * 4 + 3];
      *(float4*)(cp + o4 * 4) = v;
    }
  }

  // ---- conv1(cat) + embconv(emb) -> pre (16) ----
  float pre[16];
#pragma unroll
  for (int j = 0; j < 16; ++j) pre[j] = conv1_b[j] + embconv_b[j];

#pragma unroll
  for (int c = 0; c < 64; ++c) {
    float xv = acc[c];
    const float* wr = c1t + c * 16;
#pragma unroll
    for (int j4 = 0; j4 < 4; ++j4) {
      float4 w = *(const float4*)(wr + j4 * 4);
      pre[j4 * 4 + 0] = fmaf(w.x, xv, pre[j4 * 4 + 0]);
      pre[j4 * 4 + 1] = fmaf(w.y, xv, pre[j4 * 4 + 1]);
      pre[j4 * 4 + 2] = fmaf(w.z, xv, pre[j4 * 4 + 2]);
      pre[j4 * 4 + 3] = fmaf(w.w, xv, pre[j4 * 4 + 3]);
    }
  }

  int eb = b * 256 * 65536 + rem;
#pragma unroll 8
  for (int c = 0; c < 256; ++c) {
    float xv = emb[eb + c * 65536];
    const float* wr = ect + c * 16;
#pragma unroll
    for (int j4 = 0; j4 < 4; ++j4) {
      float4 w = *(const float4*)(wr + j4 * 4);
      pre[j4 * 4 + 0] = fmaf(w.x, xv, pre[j4 * 4 + 0]);
      pre[j4 * 4 + 1] = fmaf(w.y, xv, pre[j4 * 4 + 1]);
      pre[j4 * 4 + 2] = fmaf(w.z, xv, pre[j4 * 4 + 2]);
      pre[j4 * 4 + 3] = fmaf(w.w, xv, pre[j4 * 4 + 3]);
    }
  }

  // ---- leaky + store pre (NHWC16) ----
  {
    float* pp = pre_out + (size_t)pix * 16;
#pragma unroll
    for (int j4 = 0; j4 < 4; ++j4) {
      float4 v;
      float a0 = pre[j4 * 4 + 0], a1 = pre[j4 * 4 + 1];
      float a2 = pre[j4 * 4 + 2], a3 = pre[j4 * 4 + 3];
      v.x = a0 > 0.f ? a0 : a0 * LEAK;
      v.y = a1 > 0.f ? a1 : a1 * LEAK;
      v.z = a2 > 0.f ? a2 : a2 * LEAK;
      v.w = a3 > 0.f ? a3 : a3 * LEAK;
      *(float4*)(pp + j4 * 4) = v;
    }
  }
}

// ---------------------------------------------------------------------------
// KB: conv2 3x3 (16->36) + grouped local aggregation + out 1x1 (64->32, BN
// folded) + leaky -> d_out (NCHW).
// 16x16 tile / 256 threads. One 25.9KB LDS buffer [324][20] (padded rows,
// 16B-aligned b128 access, conflict-free) reused: pre tile -> conv2, then
// each cat group tile (barrier-separated). Halo zero-filled in LDS, so the
// tap loops have no bounds logic.
// ---------------------------------------------------------------------------
__global__ __launch_bounds__(256) void kb_fused(
    const float* __restrict__ cat_in, const float* __restrict__ pre_in,
    const float* __restrict__ wbuf,
    const float* __restrict__ conv2_b,
    float* __restrict__ out) {
  const float* w2t   = wbuf + 13312;  // [9][16][36]
  const float* owt   = wbuf + 18496;  // [64][32] BN-folded
  const float* obias = wbuf + 20544;  // [32]

  __shared__ __align__(16) float lds[324 * 20];  // [site][20] (16 used)

  int tid = threadIdx.x;
  int bx = blockIdx.x & 15, by = (blockIdx.x >> 4) & 15, b = blockIdx.x >> 8;
  int x0 = bx << 4, y0 = by << 4;
  int tx = tid & 15, ty = tid >> 4;

  // ---- stage pre tile (18x18x16, zero halo): 4 threads per site ----
  for (int t = tid; t < 1296; t += 256) {
    int site = t >> 2, part = t & 3;
    int sy = site / 18, sx = site - sy * 18;
    int gy = y0 + sy - 1, gx = x0 + sx - 1;
    float4 v = {0.f, 0.f, 0.f, 0.f};
    if ((unsigned)gy < 256u && (unsigned)gx < 256u)
      v = *(const float4*)(pre_in + ((size_t)((b << 16) + gy * 256 + gx)) * 16 + part * 4);
    *(float4*)(lds + site * 20 + part * 4) = v;
  }
  __syncthreads();

  // ---- conv2 -> wgt[36] ----
  float wgt[36];
#pragma unroll
  for (int o = 0; o < 36; ++o) wgt[o] = conv2_b[o];

  for (int k = 0; k < 9; ++k) {  // rolled: wgt stays statically indexed
    int ky = k / 3, kx = k - ky * 3;
    int slot = (ty + ky) * 18 + (tx + kx);
    const float* lp = lds + slot * 20;
    float4 q0 = *(const float4*)(lp + 0);
    float4 q1 = *(const float4*)(lp + 4);
    float4 q2 = *(const float4*)(lp + 8);
    float4 q3 = *(const float4*)(lp + 12);
    float pv[16] = {q0.x, q0.y, q0.z, q0.w, q1.x, q1.y, q1.z, q1.w,
                    q2.x, q2.y, q2.z, q2.w, q3.x, q3.y, q3.z, q3.w};
    const float* wp = w2t + k * 576;
#pragma unroll
    for (int i = 0; i < 16; ++i) {
      float xv = pv[i];
#pragma unroll
      for (int o4 = 0; o4 < 9; ++o4) {
        float4 w = *(const float4*)(wp + i * 36 + o4 * 4);
        wgt[o4 * 4 + 0] = fmaf(w.x, xv, wgt[o4 * 4 + 0]);
        wgt[o4 * 4 + 1] = fmaf(w.y, xv, wgt[o4 * 4 + 1]);
        wgt[o4 * 4 + 2] = fmaf(w.z, xv, wgt[o4 * 4 + 2]);
        wgt[o4 * 4 + 3] = fmaf(w.w, xv, wgt[o4 * 4 + 3]);
      }
    }
  }

  // ---- out accumulator (BN-folded bias) ----
  float o32[32];
#pragma unroll
  for (int o = 0; o < 32; ++o) o32[o] = obias[o];

  // ---- per group: stage cat tile into same LDS, taps, fold into o32 ----
#pragma unroll
  for (int g = 0; g < 4; ++g) {
    __syncthreads();  // previous contents fully consumed
    for (int t = tid; t < 1296; t += 256) {
      int site = t >> 2, part = t & 3;
      int sy = site / 18, sx = site - sy * 18;
      int gy = y0 + sy - 1, gx = x0 + sx - 1;
      float4 v = {0.f, 0.f, 0.f, 0.f};
      if ((unsigned)gy < 256u && (unsigned)gx < 256u)
        v = *(const float4*)(cat_in +
              (((size_t)(b * 4 + g) << 16) + gy * 256 + gx) * 16 + part * 4);
      *(float4*)(lds + site * 20 + part * 4) = v;
    }
    __syncthreads();

    float agg[16];
#pragma unroll
    for (int c = 0; c < 16; ++c) agg[c] = 0.f;

#pragma unroll
    for (int k = 0; k < 9; ++k) {
      const int ky = k / 3, kx = k - ky * 3;
      int slot = (ty + ky) * 18 + (tx + kx);
      const float* lp = lds + slot * 20;
      float4 c0 = *(const float4*)(lp + 0);
      float4 c1 = *(const float4*)(lp + 4);
      float4 c2 = *(const float4*)(lp + 8);
      float4 c3 = *(const float4*)(lp + 12);
      float wk = wgt[g * 9 + k];
      agg[0]  = fmaf(wk, c0.x, agg[0]);  agg[1]  = fmaf(wk, c0.y, agg[1]);
      agg[2]  = fmaf(wk, c0.z, agg[2]);  agg[3]  = fmaf(wk, c0.w, agg[3]);
      agg[4]  = fmaf(wk, c1.x, agg[4]);  agg[5]  = fmaf(wk, c1.y, agg[5]);
      agg[6]  = fmaf(wk, c1.z, agg[6]);  agg[7]  = fmaf(wk, c1.w, agg[7]);
      agg[8]  = fmaf(wk, c2.x, agg[8]);  agg[9]  = fmaf(wk, c2.y, agg[9]);
      agg[10] = fmaf(wk, c2.z, agg[10]); agg[11] = fmaf(wk, c2.w, agg[11]);
      agg[12] = fmaf(wk, c3.x, agg[12]); agg[13] = fmaf(wk, c3.y, agg[13]);
      agg[14] = fmaf(wk, c3.z, agg[14]); agg[15] = fmaf(wk, c3.w, agg[15]);
    }

    // fold agg (group channels) into o32 via BN-folded out weights
#pragma unroll
    for (int c = 0; c < 16; ++c) {
      float xv = agg[c];
      const float* wr = owt + (g * 16 + c) * 32;
#pragma unroll
      for (int o4 = 0; o4 < 8; ++o4) {
        float4 w = *(const float4*)(wr + o4 * 4);
        o32[o4 * 4 + 0] = fmaf(w.x, xv, o32[o4 * 4 + 0]);
        o32[o4 * 4 + 1] = fmaf(w.y, xv, o32[o4 * 4 + 1]);
        o32[o4 * 4 + 2] = fmaf(w.z, xv, o32[o4 * 4 + 2]);
        o32[o4 * 4 + 3] = fmaf(w.w, xv, o32[o4 * 4 + 3]);
      }
    }
  }

  // ---- leaky + store NCHW ----
  int px = x0 + tx, py = y0 + ty;
  int outbase = ((b << 5) * 256 + py) * 256 + px;
#pragma unroll
  for (int o = 0; o < 32; ++o) {
    float v = o32[o];
    v = v > 0.f ? v : v * LEAK;
    out[outbase + o * 65536] = v;
  }
}

// ---------------------------------------------------------------------------
extern "C" void kernel_launch(void* const* d_in, const int* in_sizes, int n_in,
                              void* d_out, int out_size, void* d_ws, size_t ws_size,
                              hipStream_t stream) {
  const float* high      = (const float*)d_in[0];
  const float* low       = (const float*)d_in[1];
  const float* emb       = (const float*)d_in[2];
  const float* reduce_w  = (const float*)d_in[3];
  const float* reduce_b  = (const float*)d_in[4];
  const float* conv1_w   = (const float*)d_in[5];
  const float* conv1_b   = (const float*)d_in[6];
  const float* embconv_w = (const float*)d_in[7];
  const float* embconv_b = (const float*)d_in[8];
  const float* conv2_w   = (const float*)d_in[9];
  const float* conv2_b   = (const float*)d_in[10];
  const float* out_w     = (const float*)d_in[11];
  const float* out_b     = (const float*)d_in[12];
  const float* bn_gamma  = (const float*)d_in[13];
  const float* bn_beta   = (const float*)d_in[14];
  const float* bn_mean   = (const float*)d_in[15];
  const float* bn_var    = (const float*)d_in[16];

  float* ws   = (float*)d_ws;
  float* cat  = ws;                // 16,777,216 floats (grouped NHWC16)
  float* pre  = ws + WS_PRE_OFF;   //  4,194,304 floats
  float* wbuf = ws + WS_W_OFF;     //     20,576 floats

  k0_transpose<<<81, 256, 0, stream>>>(reduce_w, conv1_w, embconv_w, conv2_w,
                                       out_w, out_b, bn_gamma, bn_beta,
                                       bn_mean, bn_var, wbuf);
  ka_fused<<<1024, 256, 0, stream>>>(high, low, emb, reduce_b, conv1_b,
                                     embconv_b, wbuf, cat, pre);
  kb_fused<<<1024, 256, 0, stream>>>(cat, pre, wbuf, conv2_b, (float*)d_out);
}